// Round 2
// baseline (213.289 us; speedup 1.0000x reference)
//
#include <hip/hip_runtime.h>

// OPT attention: B=16 T=4 E=2048 H=32 HD=64 P=4096 S=4100, M=B*T=64 rows.
// All GEMM-shaped work on mfma_f32_16x16x32_bf16 (A[m=lane&15][k=quad*8+j],
// B[n=lane&15][k=quad*8+j], D col=lane&15 row=quad*4+reg — verified layouts).
// Output dtype: FLOAT32 (reference returns f32) — R1 failed by writing bf16.

typedef float f4 __attribute__((ext_vector_type(4)));
typedef short s8v __attribute__((ext_vector_type(8)));

#define NEG_HUGE (-3.402823466e38f)

__device__ inline unsigned short f2bs(float x) {  // f32 -> bf16 bits (RNE)
  union { float f; unsigned int u; } a; a.f = x;
  unsigned int u = a.u;
  u += 0x7fffu + ((u >> 16) & 1u);
  return (unsigned short)(u >> 16);
}
__device__ inline float bs2f(unsigned short s) {
  union { unsigned int u; float f; } a; a.u = ((unsigned int)s) << 16;
  return a.f;
}
__device__ inline unsigned long long pack4(float a, float b, float c, float d) {
  return (unsigned long long)f2bs(a) | ((unsigned long long)f2bs(b) << 16)
       | ((unsigned long long)f2bs(c) << 32) | ((unsigned long long)f2bs(d) << 48);
}
__device__ inline s8v cvt8(f4 a, f4 b) {
  s8v r;
  r[0]=(short)f2bs(a[0]); r[1]=(short)f2bs(a[1]); r[2]=(short)f2bs(a[2]); r[3]=(short)f2bs(a[3]);
  r[4]=(short)f2bs(b[0]); r[5]=(short)f2bs(b[1]); r[6]=(short)f2bs(b[2]); r[7]=(short)f2bs(b[3]);
  return r;
}
__device__ inline f4 mfma16(s8v a, s8v b, f4 c) {
  return __builtin_amdgcn_mfma_f32_16x16x32_bf16(a, b, c, 0, 0, 0);
}
__device__ inline f4 fzero() { f4 z = {0.f,0.f,0.f,0.f}; return z; }
__device__ inline float wave_sum(float v) {
  #pragma unroll
  for (int off = 32; off; off >>= 1) v += __shfl_xor(v, off, 64);
  return v;
}

// ---------------- Kernel 1: QKV projection, split-K partials -----------------
// grid (96, 4): x = 64-col block over N=3*2048, y = k-split (512 k each)
__global__ __launch_bounds__(256) void k_qkv(
    const float* __restrict__ hs, const float* __restrict__ Wq,
    const float* __restrict__ Wk, const float* __restrict__ Wv,
    float* __restrict__ part) {
  __shared__ __align__(16) unsigned short As[64 * 264];
  const int n0 = blockIdx.x * 64;
  const int ksb = blockIdx.y;
  const int p = n0 >> 11;
  const int c0 = n0 & 2047;
  const float* W = (p == 0) ? Wq : (p == 1) ? Wk : Wv;
  const int t = threadIdx.x, lane = t & 63, w = t >> 6;
  const int cl = lane & 15, quad = lane >> 4;

  f4 acc[4];
  #pragma unroll
  for (int i = 0; i < 4; ++i) acc[i] = fzero();

  const int cw = c0 + w * 16 + cl;  // W row (output col within projection)
  for (int kt = 0; kt < 2; ++kt) {
    const int k0 = ksb * 512 + kt * 256;
    __syncthreads();
    // stage A tile [64][256] f32 -> bf16 LDS (row stride 264 to break conflicts)
    #pragma unroll
    for (int i = 0; i < 16; ++i) {
      int idx4 = t + (i << 8);          // 0..4095 float4s
      int row = idx4 >> 6;
      int col = (idx4 & 63) << 2;
      f4 v = *reinterpret_cast<const f4*>(hs + row * 2048 + k0 + col);
      *reinterpret_cast<unsigned long long*>(&As[row * 264 + col]) =
          pack4(v[0], v[1], v[2], v[3]);
    }
    __syncthreads();
    const float* wbase = W + (size_t)cw * 2048 + k0;
    #pragma unroll
    for (int ks2 = 0; ks2 < 8; ++ks2) {
      const int kb = ks2 * 32 + quad * 8;
      f4 w0 = *reinterpret_cast<const f4*>(wbase + kb);
      f4 w1 = *reinterpret_cast<const f4*>(wbase + kb + 4);
      s8v bf = cvt8(w0, w1);
      #pragma unroll
      for (int mt = 0; mt < 4; ++mt) {
        s8v af = *reinterpret_cast<const s8v*>(&As[(mt * 16 + cl) * 264 + kb]);
        acc[mt] = mfma16(af, bf, acc[mt]);
      }
    }
  }
  float* outp = part + (size_t)ksb * 64 * 6144;
  #pragma unroll
  for (int mt = 0; mt < 4; ++mt)
    #pragma unroll
    for (int rg = 0; rg < 4; ++rg) {
      int r = mt * 16 + quad * 4 + rg;
      outp[r * 6144 + n0 + w * 16 + cl] = acc[mt][rg];
    }
}

// ------------- Kernel 2: reduce partials + bias, layout q/k/v ----------------
__global__ __launch_bounds__(256) void k_qkv_red(
    const float* __restrict__ part, const float* __restrict__ bq,
    const float* __restrict__ bk, const float* __restrict__ bv,
    unsigned short* __restrict__ qws, float* __restrict__ knew,
    float* __restrict__ vnew) {
  int idx = blockIdx.x * 256 + threadIdx.x;   // < 393216
  int r = idx / 6144;
  int n = idx - r * 6144;
  float s = part[idx] + part[idx + 393216] + part[idx + 786432] + part[idx + 1179648];
  int c = n & 2047, p = n >> 11;
  int h = c >> 6, d = c & 63;
  int b = r >> 2, tt = r & 3;
  if (p == 0) {
    s = (s + bq[c]) * 0.125f;                  // query pre-scale
    qws[h * 4608 + r * 72 + d] = f2bs(s);      // [H][64][72] bf16
  } else if (p == 1) {
    knew[((h * 16 + b) * 4 + tt) * 64 + d] = s + bk[c];
  } else {
    vnew[((h * 16 + b) * 4 + tt) * 64 + d] = s + bv[c];
  }
}

// --------- Kernel 3: flash partial attention over past KV chunks -------------
// grid 512: h = bx&31, chunk = bx>>5 (256 past positions each)
__global__ __launch_bounds__(256) void k_flash(
    const unsigned short* __restrict__ qws, const float* __restrict__ Kp,
    const float* __restrict__ Vp, const float* __restrict__ mask,
    float* __restrict__ Opart, float* __restrict__ mpart,
    float* __restrict__ lpart) {
  __shared__ __align__(16) unsigned short Qs[64 * 72];
  __shared__ __align__(16) float SC[64 * 260];
  __shared__ float mrow[64];
  __shared__ float red[256];
  const int bx = blockIdx.x;
  const int h = bx & 31, cch = bx >> 5;
  const int s0 = cch * 256;
  const int t = threadIdx.x, lane = t & 63, w = t >> 6;
  const int cl = lane & 15, quad = lane >> 4;
  const float* Kh = Kp + (size_t)h * 4096 * 64;
  const float* Vh = Vp + (size_t)h * 4096 * 64;

  {  // stage Q tile (already bf16, padded layout identical to global)
    const uint4* s4 = reinterpret_cast<const uint4*>(qws + h * 4608);
    uint4* d4 = reinterpret_cast<uint4*>(Qs);
    for (int i = t; i < 576; i += 256) d4[i] = s4[i];
  }
  __syncthreads();

  s8v afr[4][2];
  #pragma unroll
  for (int mt = 0; mt < 4; ++mt)
    #pragma unroll
    for (int k2 = 0; k2 < 2; ++k2)
      afr[mt][k2] = *reinterpret_cast<const s8v*>(
          &Qs[(mt * 16 + cl) * 72 + k2 * 32 + quad * 8]);

  // QK^T: wave w handles s-subtiles nt = 4w..4w+3
  #pragma unroll
  for (int ni = 0; ni < 4; ++ni) {
    const int nt = w * 4 + ni;
    const int srow = s0 + nt * 16 + cl;
    const float* kr = Kh + (size_t)srow * 64 + quad * 8;
    f4 qa[4];
    #pragma unroll
    for (int mt = 0; mt < 4; ++mt) qa[mt] = fzero();
    #pragma unroll
    for (int k2 = 0; k2 < 2; ++k2) {
      f4 k0v = *reinterpret_cast<const f4*>(kr + k2 * 32);
      f4 k1v = *reinterpret_cast<const f4*>(kr + k2 * 32 + 4);
      s8v bf = cvt8(k0v, k1v);
      #pragma unroll
      for (int mt = 0; mt < 4; ++mt) qa[mt] = mfma16(afr[mt][k2], bf, qa[mt]);
    }
    #pragma unroll
    for (int mt = 0; mt < 4; ++mt)
      #pragma unroll
      for (int rg = 0; rg < 4; ++rg) {
        int r = mt * 16 + quad * 4 + rg;
        int sl = nt * 16 + cl;
        float v = qa[mt][rg] + mask[(size_t)r * 4100 + s0 + sl];
        SC[r * 260 + sl] = fmaxf(v, NEG_HUGE);
      }
  }
  __syncthreads();

  // chunk-local softmax stats; exp in place
  {
    const int r = lane, base = w * 64;
    float mx = NEG_HUGE;
    #pragma unroll
    for (int j = 0; j < 64; j += 4) {
      f4 v = *reinterpret_cast<const f4*>(&SC[r * 260 + base + j]);
      mx = fmaxf(fmaxf(fmaxf(mx, v[0]), v[1]), fmaxf(v[2], v[3]));
    }
    red[w * 64 + r] = mx;
  }
  __syncthreads();
  if (t < 64) {
    float m = fmaxf(fmaxf(red[t], red[64 + t]), fmaxf(red[128 + t], red[192 + t]));
    mrow[t] = m;
    mpart[(h * 16 + cch) * 64 + t] = m;
  }
  __syncthreads();
  {
    const int r = lane, base = w * 64;
    const float m = mrow[r];
    float sum = 0.f;
    #pragma unroll
    for (int j = 0; j < 64; j += 4) {
      f4 v = *reinterpret_cast<f4*>(&SC[r * 260 + base + j]);
      f4 e;
      e[0] = __expf(v[0] - m); e[1] = __expf(v[1] - m);
      e[2] = __expf(v[2] - m); e[3] = __expf(v[3] - m);
      *reinterpret_cast<f4*>(&SC[r * 260 + base + j]) = e;
      sum += e[0] + e[1] + e[2] + e[3];
    }
    red[w * 64 + r] = sum;
  }
  __syncthreads();
  if (t < 64)
    lpart[(h * 16 + cch) * 64 + t] = red[t] + red[64 + t] + red[128 + t] + red[192 + t];
  __syncthreads();

  // PV: wave w owns d-tile nt = w (cols w*16..w*16+15)
  f4 oacc[4];
  #pragma unroll
  for (int mt = 0; mt < 4; ++mt) oacc[mt] = fzero();
  const int dcol = w * 16 + cl;
  #pragma unroll
  for (int k2 = 0; k2 < 8; ++k2) {
    const int sb = k2 * 32 + quad * 8;
    s8v bf;
    #pragma unroll
    for (int j = 0; j < 8; ++j)
      bf[j] = (short)f2bs(Vh[(size_t)(s0 + sb + j) * 64 + dcol]);
    #pragma unroll
    for (int mt = 0; mt < 4; ++mt) {
      const int row = mt * 16 + cl;
      f4 p0 = *reinterpret_cast<const f4*>(&SC[row * 260 + sb]);
      f4 p1 = *reinterpret_cast<const f4*>(&SC[row * 260 + sb + 4]);
      oacc[mt] = mfma16(cvt8(p0, p1), bf, oacc[mt]);
    }
  }
  float* ob = Opart + (size_t)(h * 16 + cch) * 64 * 64;
  #pragma unroll
  for (int mt = 0; mt < 4; ++mt)
    #pragma unroll
    for (int rg = 0; rg < 4; ++rg) {
      int r = mt * 16 + quad * 4 + rg;
      ob[r * 64 + dcol] = oacc[mt][rg];
    }
}

// ------- Kernel 4: merge chunk partials + 4 new-token scores per (b,h) -------
__global__ __launch_bounds__(64) void k_merge(
    const unsigned short* __restrict__ qws, const float* __restrict__ knew,
    const float* __restrict__ vnew, const float* __restrict__ mask,
    const float* __restrict__ Opart, const float* __restrict__ mpart,
    const float* __restrict__ lpart, unsigned short* __restrict__ attn) {
  const int bx = blockIdx.x;
  const int h = bx & 31, b = bx >> 5;
  const int d = threadIdx.x;
  for (int tt = 0; tt < 4; ++tt) {
    const int r = b * 4 + tt;
    float qd = bs2f(qws[h * 4608 + r * 72 + d]);
    float scn[4];
    #pragma unroll
    for (int tp = 0; tp < 4; ++tp) {
      float kn = knew[((h * 16 + b) * 4 + tp) * 64 + d];
      float s = wave_sum(qd * kn);
      s += mask[(size_t)r * 4100 + 4096 + tp];
      scn[tp] = fmaxf(s, NEG_HUGE);
    }
    float mi[16], li[16];
    float mtot = NEG_HUGE;
    #pragma unroll
    for (int i = 0; i < 16; ++i) {
      mi[i] = mpart[(h * 16 + i) * 64 + r];
      li[i] = lpart[(h * 16 + i) * 64 + r];
      mtot = fmaxf(mtot, mi[i]);
    }
    #pragma unroll
    for (int tp = 0; tp < 4; ++tp) mtot = fmaxf(mtot, scn[tp]);
    float ltot = 0.f, od = 0.f;
    #pragma unroll
    for (int i = 0; i < 16; ++i) {
      float fct = __expf(mi[i] - mtot);
      ltot += li[i] * fct;
      od += Opart[((size_t)(h * 16 + i) * 64 + r) * 64 + d] * fct;
    }
    #pragma unroll
    for (int tp = 0; tp < 4; ++tp) {
      float e = __expf(scn[tp] - mtot);
      ltot += e;
      od += e * vnew[((h * 16 + b) * 4 + tp) * 64 + d];
    }
    attn[(size_t)r * 2048 + h * 64 + d] = f2bs(od / ltot);
  }
}

// -------------- Kernel 5: output projection, split-K partials ----------------
// grid (32, 8): x = 64-col block, y = k-split (256 k each)
__global__ __launch_bounds__(256) void k_out(
    const unsigned short* __restrict__ attn, const float* __restrict__ Wo,
    float* __restrict__ part) {
  __shared__ __align__(16) unsigned short As[64 * 264];
  const int n0 = blockIdx.x * 64;
  const int ksb = blockIdx.y;
  const int k0 = ksb * 256;
  const int t = threadIdx.x, lane = t & 63, w = t >> 6;
  const int cl = lane & 15, quad = lane >> 4;
  #pragma unroll
  for (int i = 0; i < 8; ++i) {
    int idx8 = t + (i << 8);          // 0..2047 short8s
    int row = idx8 >> 5;
    int col = (idx8 & 31) << 3;
    *reinterpret_cast<uint4*>(&As[row * 264 + col]) =
        *reinterpret_cast<const uint4*>(attn + (size_t)row * 2048 + k0 + col);
  }
  __syncthreads();
  f4 acc[4];
  #pragma unroll
  for (int i = 0; i < 4; ++i) acc[i] = fzero();
  const int cw = n0 + w * 16 + cl;
  const float* wbase = Wo + (size_t)cw * 2048 + k0;
  #pragma unroll
  for (int ks2 = 0; ks2 < 8; ++ks2) {
    const int kb = ks2 * 32 + quad * 8;
    f4 w0 = *reinterpret_cast<const f4*>(wbase + kb);
    f4 w1 = *reinterpret_cast<const f4*>(wbase + kb + 4);
    s8v bf = cvt8(w0, w1);
    #pragma unroll
    for (int mt = 0; mt < 4; ++mt) {
      s8v af = *reinterpret_cast<const s8v*>(&As[(mt * 16 + cl) * 264 + kb]);
      acc[mt] = mfma16(af, bf, acc[mt]);
    }
  }
  float* op = part + (size_t)ksb * 64 * 2048;
  #pragma unroll
  for (int mt = 0; mt < 4; ++mt)
    #pragma unroll
    for (int rg = 0; rg < 4; ++rg) {
      int r = mt * 16 + quad * 4 + rg;
      op[r * 2048 + n0 + w * 16 + cl] = acc[mt][rg];
    }
}

// ----------------- Kernel 6: reduce + bias -> f32 output ---------------------
__global__ __launch_bounds__(256) void k_out_red(
    const float* __restrict__ part, const float* __restrict__ bo,
    float* __restrict__ out) {
  int idx = blockIdx.x * 256 + threadIdx.x;   // < 131072
  int n = idx & 2047;
  float s = bo[n];
  #pragma unroll
  for (int ks = 0; ks < 8; ++ks) s += part[idx + ks * 131072];
  out[idx] = s;
}

extern "C" void kernel_launch(void* const* d_in, const int* in_sizes, int n_in,
                              void* d_out, int out_size, void* d_ws, size_t ws_size,
                              hipStream_t stream) {
  const float* hs   = (const float*)d_in[0];
  const float* pk   = (const float*)d_in[1];
  const float* pv   = (const float*)d_in[2];
  const float* mask = (const float*)d_in[3];
  const float* Wq   = (const float*)d_in[4];
  const float* bq   = (const float*)d_in[5];
  const float* Wk   = (const float*)d_in[6];
  const float* bk   = (const float*)d_in[7];
  const float* Wv   = (const float*)d_in[8];
  const float* bv   = (const float*)d_in[9];
  const float* Wo   = (const float*)d_in[10];
  const float* bo   = (const float*)d_in[11];

  float* f = (float*)d_ws;                   // ~20.7 MB of workspace used
  float* qkv_part = f;                       // [4][64][6144]
  float* o_part   = qkv_part + 1572864;      // [8][64][2048]
  float* Opart    = o_part   + 1048576;      // [32][16][64][64]
  float* mpart    = Opart    + 2097152;      // [32][16][64]
  float* lpart    = mpart    + 32768;
  float* knew     = lpart    + 32768;        // [32][16][4][64]
  float* vnew     = knew     + 131072;
  unsigned short* qws  = (unsigned short*)(vnew + 131072);  // [32][64][72] bf16
  unsigned short* attn = qws + 147456;                      // [64][2048] bf16

  k_qkv<<<dim3(96, 4), 256, 0, stream>>>(hs, Wq, Wk, Wv, qkv_part);
  k_qkv_red<<<1536, 256, 0, stream>>>(qkv_part, bq, bk, bv, qws, knew, vnew);
  k_flash<<<512, 256, 0, stream>>>(qws, pk, pv, mask, Opart, mpart, lpart);
  k_merge<<<512, 64, 0, stream>>>(qws, knew, vnew, mask, Opart, mpart, lpart, attn);
  k_out<<<dim3(32, 8), 256, 0, stream>>>(attn, Wo, o_part);
  k_out_red<<<512, 256, 0, stream>>>(o_part, bo, (float*)d_out);
}